// Round 10
// baseline (229.476 us; speedup 1.0000x reference)
//
#include <hip/hip_runtime.h>
#include <math.h>

#define N 4096
#define DQ 128
#define DIN 64
#define DC 32
#define NT 9          // full B panel: 9 n-tiles (128 v cols + z tile)
#define PST9 144
#define PST1 16
#define NIT 256       // N/16 i-tiles

typedef __attribute__((ext_vector_type(8))) short short8;
typedef __attribute__((ext_vector_type(8))) _Float16 half8;
typedef __attribute__((ext_vector_type(4))) float f32x4;

__device__ __forceinline__ unsigned short f2h(float x) {
  return __builtin_bit_cast(unsigned short, (_Float16)x);
}
__device__ __forceinline__ void async16(unsigned short* lds, const unsigned short* g) {
  __builtin_amdgcn_global_load_lds(
      (const __attribute__((address_space(1))) void*)g,
      (__attribute__((address_space(3))) void*)lds, 16, 0, 0);
}

// ---- kExp: Ef = f16(exp(trans)) in MFMA A-frag layout (the one transpose) ----
__global__ __launch_bounds__(256) void kExp(const float* __restrict__ trans,
                                            unsigned short* __restrict__ Ef) {
  __shared__ float sh[32 * 65];
  const int tid = threadIdx.x;
  const int ig = blockIdx.x;        // i-group of 64
  const int kt = blockIdx.y;        // k-tile of 32
  const int r = tid >> 3;
  const int c8 = (tid & 7) * 8;
  const float* src = &trans[((size_t)kt * 32 + r) * N + ig * 64 + c8];
  const float4 v0 = *(const float4*)src;
  const float4 v1 = *(const float4*)(src + 4);
  float* d = &sh[r * 65 + c8];
  d[0] = __expf(v0.x); d[1] = __expf(v0.y); d[2] = __expf(v0.z); d[3] = __expf(v0.w);
  d[4] = __expf(v1.x); d[5] = __expf(v1.y); d[6] = __expf(v1.z); d[7] = __expf(v1.w);
  __syncthreads();
  const int itl = tid >> 6;
  const int lane = tid & 63;
  const int quad = lane >> 4, l15 = lane & 15;
  const int col = itl * 16 + l15;
  unsigned short hb[8];
#pragma unroll
  for (int jj = 0; jj < 8; ++jj) hb[jj] = f2h(sh[(quad * 8 + jj) * 65 + col]);
  const short8 s = {(short)hb[0], (short)hb[1], (short)hb[2], (short)hb[3],
                    (short)hb[4], (short)hb[5], (short)hb[6], (short)hb[7]};
  *(short8*)(Ef + (((size_t)kt * NIT + ig * 4 + itl) * 64 + lane) * 8) = s;
}

// ---- shared epilogue: p*(h@W_av+b_av) -> single f16 into LDS tile -----------
__device__ __forceinline__ void v_phase(const float* hs_row, float p,
    const float* __restrict__ W_av_k, const float* __restrict__ b_av_k,
    int r, int d4, unsigned short* shh) {
  float a[4] = {b_av_k[d4], b_av_k[d4 + 1], b_av_k[d4 + 2], b_av_k[d4 + 3]};
  for (int c = 0; c < DQ; ++c) {
    const float hv = hs_row[c];
    const float4 w = *(const float4*)&W_av_k[c * DQ + d4];
    a[0] += hv * w.x; a[1] += hv * w.y; a[2] += hv * w.z; a[3] += hv * w.w;
  }
  const int nt = d4 >> 4;
#pragma unroll
  for (int e = 0; e < 4; ++e)
    shh[nt * 128 + ((d4 + e) & 15) * 8 + r] = f2h(p * a[e]);
  const int c32 = d4 >> 2;
  if (c32 < 16)
    shh[8 * 128 + c32 * 8 + r] = (c32 == 0) ? f2h(p) : 0;
}

__device__ __forceinline__ void v_store(int tid, int blk,
    const unsigned short* shh, unsigned short* __restrict__ Vf) {
  const int kt = blk >> 2, quad = blk & 3;
  if (tid < NT * 16) {
    const int nt = tid >> 4, l15 = tid & 15;
    const size_t dst = (((size_t)kt * NT + nt) * 64 + quad * 16 + l15) * 8;
    *(short8*)(Vf + dst) = *(const short8*)&shh[nt * 128 + l15 * 8];
  }
}

// ---- round 0: encode + sa + p + V' fused (8 rows per block) ----
__global__ __launch_bounds__(256) void kVS0(const float* __restrict__ x,
    const float* __restrict__ comms, const float* __restrict__ W_enc,
    const float* __restrict__ b_enc, const float* __restrict__ W_ad_k,
    const float* __restrict__ wa, const float* __restrict__ W_av_k,
    const float* __restrict__ b_av_k, unsigned short* __restrict__ Vf) {
  __shared__ float xs[8][96];
  __shared__ float hs[8][DQ];
  __shared__ float u[DQ];
  __shared__ float pb[8];
  __shared__ __align__(16) unsigned short shh[NT * 128];
  const int tid = threadIdx.x;
  const int blk = blockIdx.x;
  if (tid < 128) {
    const float4 v = *(const float4*)&x[(size_t)blk * 8 * DIN + tid * 4];
    const int idx = tid * 4, r = idx >> 6, c = idx & 63;
    xs[r][c] = v.x; xs[r][c + 1] = v.y; xs[r][c + 2] = v.z; xs[r][c + 3] = v.w;
  } else if (tid < 192) {
    const int t = tid - 128;
    const float4 v = *(const float4*)&comms[(size_t)blk * 8 * DC + t * 4];
    const int idx = t * 4, r = idx >> 5, c = idx & 31;
    xs[r][64 + c] = v.x; xs[r][64 + c + 1] = v.y; xs[r][64 + c + 2] = v.z; xs[r][64 + c + 3] = v.w;
  }
  if (tid < DQ) {
    float s = 0.f;
    const float* wrow = &W_ad_k[tid * DQ];
    for (int q = 0; q < DQ; ++q) s += wrow[q] * wa[q];
    u[tid] = s;
  }
  __syncthreads();
  const int r = tid >> 5;
  const int c32 = tid & 31;
  const int d4 = c32 * 4;
  {
    float a0 = b_enc[d4], a1 = b_enc[d4 + 1], a2 = b_enc[d4 + 2], a3 = b_enc[d4 + 3];
    for (int c = 0; c < 96; ++c) {
      const float hv = xs[r][c];
      const float4 w = *(const float4*)&W_enc[c * DQ + d4];
      a0 += hv * w.x; a1 += hv * w.y; a2 += hv * w.z; a3 += hv * w.w;
    }
    hs[r][d4] = a0; hs[r][d4 + 1] = a1; hs[r][d4 + 2] = a2; hs[r][d4 + 3] = a3;
  }
  __syncthreads();
  float part = 0.f;
  for (int c = c32; c < DQ; c += 32) part += hs[r][c] * u[c];
#pragma unroll
  for (int m = 16; m > 0; m >>= 1) part += __shfl_xor(part, m, 32);
  if (c32 == 0) pb[r] = __expf(part);
  __syncthreads();
  v_phase(hs[r], pb[r], W_av_k, b_av_k, r, d4, shh);
  __syncthreads();
  v_store(tid, blk, shh, Vf);
}

// ---- round 1: P-reduce -> h + sa + p + V' (full panel) ----
__global__ __launch_bounds__(256) void kVSR(const float* __restrict__ P,
    const float* __restrict__ W_ad_k, const float* __restrict__ wa,
    const float* __restrict__ W_av_k, const float* __restrict__ b_av_k,
    unsigned short* __restrict__ Vf, int ksplit) {
  __shared__ float hs[8][DQ];
  __shared__ float u[DQ];
  __shared__ float pb[8];
  __shared__ __align__(16) unsigned short shh[NT * 128];
  const int tid = threadIdx.x;
  const int r = tid >> 5;
  const int c32 = tid & 31;
  const int d4 = c32 * 4;
  const int j = blockIdx.x * 8 + r;
  if (tid < DQ) {
    float s = 0.f;
    const float* wrow = &W_ad_k[tid * DQ];
    for (int q = 0; q < DQ; ++q) s += wrow[q] * wa[q];
    u[tid] = s;
  }
  float4 num = {0.f, 0.f, 0.f, 0.f};
  float den = 0.f;
  for (int s = 0; s < ksplit; ++s) {
    const float* b = &P[((size_t)s * N + j) * PST9];
    const float4 v = *(const float4*)&b[d4];
    num.x += v.x; num.y += v.y; num.z += v.z; num.w += v.w;
    den += b[128];
  }
  const float inv = 1.f / den;
  hs[r][d4] = num.x * inv; hs[r][d4 + 1] = num.y * inv;
  hs[r][d4 + 2] = num.z * inv; hs[r][d4 + 3] = num.w * inv;
  __syncthreads();
  float part = 0.f;
  for (int c = c32; c < DQ; c += 32) part += hs[r][c] * u[c];
#pragma unroll
  for (int m = 16; m > 0; m >>= 1) part += __shfl_xor(part, m, 32);
  if (c32 == 0) pb[r] = __expf(part);
  __syncthreads();
  v_phase(hs[r], pb[r], W_av_k, b_av_k, r, d4, shh);
  __syncthreads();
  v_store(tid, blockIdx.x, shh, Vf);
}

// ---- round 2: P-reduce -> h + sa + p + CONTRACTED V' (v.W_dec, p) ----
__global__ __launch_bounds__(256) void kVSRc(const float* __restrict__ P,
    const float* __restrict__ W_ad_k, const float* __restrict__ wa,
    const float* __restrict__ W_av_k, const float* __restrict__ b_av_k,
    const float* __restrict__ W_dec, unsigned short* __restrict__ Vc,
    int ksplit) {
  __shared__ float hs[8][DQ];
  __shared__ float u[DQ];
  __shared__ float pb[8];
  const int tid = threadIdx.x;
  const int r = tid >> 5;
  const int c32 = tid & 31;
  const int d4 = c32 * 4;
  const int j = blockIdx.x * 8 + r;
  if (tid < DQ) {
    float s = 0.f;
    const float* wrow = &W_ad_k[tid * DQ];
    for (int q = 0; q < DQ; ++q) s += wrow[q] * wa[q];
    u[tid] = s;
  }
  float4 num = {0.f, 0.f, 0.f, 0.f};
  float den = 0.f;
  for (int s = 0; s < ksplit; ++s) {
    const float* b = &P[((size_t)s * N + j) * PST9];
    const float4 v = *(const float4*)&b[d4];
    num.x += v.x; num.y += v.y; num.z += v.z; num.w += v.w;
    den += b[128];
  }
  const float inv = 1.f / den;
  hs[r][d4] = num.x * inv; hs[r][d4 + 1] = num.y * inv;
  hs[r][d4 + 2] = num.z * inv; hs[r][d4 + 3] = num.w * inv;
  __syncthreads();
  float part = 0.f;
  for (int c = c32; c < DQ; c += 32) part += hs[r][c] * u[c];
#pragma unroll
  for (int m = 16; m > 0; m >>= 1) part += __shfl_xor(part, m, 32);
  if (c32 == 0) pb[r] = __expf(part);
  __syncthreads();
  float a[4] = {b_av_k[d4], b_av_k[d4 + 1], b_av_k[d4 + 2], b_av_k[d4 + 3]};
  for (int c = 0; c < DQ; ++c) {
    const float hv = hs[r][c];
    const float4 w = *(const float4*)&W_av_k[c * DQ + d4];
    a[0] += hv * w.x; a[1] += hv * w.y; a[2] += hv * w.z; a[3] += hv * w.w;
  }
  float vd = a[0] * W_dec[d4] + a[1] * W_dec[d4 + 1]
           + a[2] * W_dec[d4 + 2] + a[3] * W_dec[d4 + 3];
#pragma unroll
  for (int m = 16; m > 0; m >>= 1) vd += __shfl_xor(vd, m, 32);
  const float p = pb[r];
  if (c32 < 16) {
    const int blk = blockIdx.x;
    const size_t ix = (((size_t)(blk >> 2)) * 64 + (blk & 3) * 16 + c32) * 8 + r;
    Vc[ix] = (c32 == 0) ? f2h(p * vd) : (c32 == 1) ? f2h(p) : 0;
  }
}

// ---- B-stationary MFMA GEMM: P[s][i][d] = sum_j E[j][i]*V'[j][d] ------------
// Block = 4 waves, 8 i-tiles. B panel for an 8-step k-chunk (NTT KB/step)
// staged ONCE into LDS via global_load_lds -> single barrier -> barrier-free
// i-loop: each wave owns 2 i-tiles, A-frags in registers, MFMA vs LDS B.
template <int NTT, int PST>
__global__ __launch_bounds__(256) void kGemm(
    const unsigned short* __restrict__ Ef, const unsigned short* __restrict__ Vf,
    float* __restrict__ P, int nsteps) {
  __shared__ __align__(16) unsigned short lds[8 * NTT * 512];
  const int tid = threadIdx.x;
  const int w = tid >> 6, lane = tid & 63;
  const int quad = lane >> 4, l15 = lane & 15;
  const int it0 = blockIdx.x * 8 + w * 2;        // this wave's 2 i-tiles

  f32x4 acc[2][NTT];
#pragma unroll
  for (int ti = 0; ti < 2; ++ti)
#pragma unroll
    for (int nt = 0; nt < NTT; ++nt) acc[ti][nt] = (f32x4){0.f, 0.f, 0.f, 0.f};

  for (int ss = 0; ss < nsteps; ss += 8) {       // 8-step chunks (nsteps=8 typ.)
    const size_t kt0 = (size_t)blockIdx.y * nsteps + ss;
    if (ss) __syncthreads();                     // prior chunk fully consumed
    for (int c = w; c < 8 * NTT; c += 4)
      async16(&lds[c * 512], Vf + (kt0 * NTT + c) * 512 + lane * 8);
    // A-frags for both tiles, all 8 steps (64 VGPRs) — overlap with staging
    half8 A[2][8];
#pragma unroll
    for (int ti = 0; ti < 2; ++ti)
#pragma unroll
      for (int s = 0; s < 8; ++s)
        A[ti][s] = __builtin_bit_cast(half8,
            *(const short8*)(Ef + (((kt0 + s) * NIT + it0 + ti) * 64 + lane) * 8));
    __syncthreads();                             // drains staging (vmcnt 0)
#pragma unroll
    for (int s = 0; s < 8; ++s) {
#pragma unroll
      for (int nt = 0; nt < NTT; ++nt) {
        const half8 Bh = __builtin_bit_cast(half8,
            *(const short8*)(lds + (s * NTT + nt) * 512 + lane * 8));
        acc[0][nt] = __builtin_amdgcn_mfma_f32_16x16x32_f16(A[0][s], Bh, acc[0][nt], 0, 0, 0);
        acc[1][nt] = __builtin_amdgcn_mfma_f32_16x16x32_f16(A[1][s], Bh, acc[1][nt], 0, 0, 0);
      }
    }
  }
  float* Pb = P + (size_t)blockIdx.y * N * PST;
#pragma unroll
  for (int ti = 0; ti < 2; ++ti) {
#pragma unroll
    for (int nt = 0; nt < NTT; ++nt) {
#pragma unroll
      for (int r = 0; r < 4; ++r) {
        const int i = (it0 + ti) * 16 + quad * 4 + r;
        Pb[(size_t)i * PST + nt * 16 + l15] = acc[ti][nt][r];
      }
    }
  }
}

// ---- final: out[i] = numc/den + b_dec (P3 has 2 live cols) ----
__global__ __launch_bounds__(256) void kOut(const float* __restrict__ P3,
    const float* __restrict__ b_dec, const int* __restrict__ mask,
    float* __restrict__ out, int ksplit) {
  const int i = blockIdx.x * 256 + threadIdx.x;
  float num = 0.f, den = 0.f;
  for (int s = 0; s < ksplit; ++s) {
    const float* b = &P3[((size_t)s * N + i) * PST1];
    num += b[0];
    den += b[1];
  }
  out[i] = (mask[i] == 0) ? -INFINITY : num / den + b_dec[0];
}

extern "C" void kernel_launch(void* const* d_in, const int* in_sizes, int n_in,
                              void* d_out, int out_size, void* d_ws, size_t ws_size,
                              hipStream_t stream) {
  (void)in_sizes; (void)n_in; (void)out_size;
  const float* x     = (const float*)d_in[0];
  const float* comms = (const float*)d_in[1];
  const float* trans = (const float*)d_in[2];
  const int*   mask  = (const int*)d_in[3];
  const float* W_enc = (const float*)d_in[4];
  const float* b_enc = (const float*)d_in[5];
  const float* W_ad  = (const float*)d_in[6];
  // d_in[7]=b_ad, d_in[9]=b_att cancel inside the row softmax
  const float* w_att = (const float*)d_in[8];
  const float* W_av  = (const float*)d_in[10];
  const float* b_av  = (const float*)d_in[11];
  const float* W_dec = (const float*)d_in[12];
  const float* b_dec = (const float*)d_in[13];
  float* out         = (float*)d_out;

  char* ws = (char*)d_ws;
  unsigned short* Vf = (unsigned short*)ws;  ws += (size_t)(N / 32) * NT * 512 * 2;
  unsigned short* Vc = (unsigned short*)ws;  ws += (size_t)(N / 32) * 512 * 2;
  unsigned short* Ef = (unsigned short*)ws;  ws += (size_t)N * N * 2;
  float* P  = (float*)ws;
  const size_t fixedB = (size_t)(N / 32) * (NT + 1) * 1024 + (size_t)N * N * 2;
  const size_t perB   = (size_t)N * (PST9 + PST1) * 4;
  const int ksplit = (ws_size >= fixedB + 16 * perB) ? 16 : 8;
  float* P3 = P + (size_t)ksplit * N * PST9;
  const int nsteps = (N / ksplit) >> 5;

  kExp<<<dim3(64, 128), 256, 0, stream>>>(trans, Ef);
  kVS0<<<N / 8, 256, 0, stream>>>(x, comms, W_enc, b_enc, W_ad, w_att,
                                  W_av, b_av, Vf);
  kGemm<NT, PST9><<<dim3(NIT / 8, ksplit), 256, 0, stream>>>(Ef, Vf, P, nsteps);

  kVSR<<<N / 8, 256, 0, stream>>>(P, W_ad + (size_t)1 * DQ * DQ,
                                  w_att + 2 * DQ, W_av + (size_t)1 * DQ * DQ,
                                  b_av + DQ, Vf, ksplit);
  kGemm<NT, PST9><<<dim3(NIT / 8, ksplit), 256, 0, stream>>>(Ef, Vf, P, nsteps);

  kVSRc<<<N / 8, 256, 0, stream>>>(P, W_ad + (size_t)2 * DQ * DQ,
                                   w_att + 4 * DQ, W_av + (size_t)2 * DQ * DQ,
                                   b_av + 2 * DQ, W_dec, Vc, ksplit);
  kGemm<1, PST1><<<dim3(NIT / 8, ksplit), 256, 0, stream>>>(Ef, Vc, P3, nsteps);

  kOut<<<N / 256, 256, 0, stream>>>(P3, b_dec, mask, out, ksplit);
}

// Round 11
// 213.244 us; speedup vs baseline: 1.0761x; 1.0761x over previous
//
#include <hip/hip_runtime.h>
#include <math.h>

#define N 4096
#define DQ 128
#define DIN 64
#define DC 32
#define NT 9          // full B panel: 9 n-tiles (128 v cols + z tile)
#define PST9 144
#define PST1 16
#define NIT 256       // N/16 i-tiles
#define KB 4          // grid k-splits
#define SW 8          // k-steps per wave: N / KB / 32 rows / 4 waves

typedef __attribute__((ext_vector_type(8))) short short8;
typedef __attribute__((ext_vector_type(8))) _Float16 half8;
typedef __attribute__((ext_vector_type(4))) float f32x4;

__device__ __forceinline__ unsigned short f2h(float x) {
  return __builtin_bit_cast(unsigned short, (_Float16)x);
}
__device__ __forceinline__ void async16(unsigned short* lds, const unsigned short* g) {
  __builtin_amdgcn_global_load_lds(
      (const __attribute__((address_space(1))) void*)g,
      (__attribute__((address_space(3))) void*)lds, 16, 0, 0);
}

// ---- kExp: Ef = f16(exp(trans)) in MFMA A-frag layout (the one transpose) ----
__global__ __launch_bounds__(256) void kExp(const float* __restrict__ trans,
                                            unsigned short* __restrict__ Ef) {
  __shared__ float sh[32 * 65];
  const int tid = threadIdx.x;
  const int ig = blockIdx.x;        // i-group of 64
  const int kt = blockIdx.y;        // k-tile of 32
  const int r = tid >> 3;
  const int c8 = (tid & 7) * 8;
  const float* src = &trans[((size_t)kt * 32 + r) * N + ig * 64 + c8];
  const float4 v0 = *(const float4*)src;
  const float4 v1 = *(const float4*)(src + 4);
  float* d = &sh[r * 65 + c8];
  d[0] = __expf(v0.x); d[1] = __expf(v0.y); d[2] = __expf(v0.z); d[3] = __expf(v0.w);
  d[4] = __expf(v1.x); d[5] = __expf(v1.y); d[6] = __expf(v1.z); d[7] = __expf(v1.w);
  __syncthreads();
  const int itl = tid >> 6;
  const int lane = tid & 63;
  const int quad = lane >> 4, l15 = lane & 15;
  const int col = itl * 16 + l15;
  unsigned short hb[8];
#pragma unroll
  for (int jj = 0; jj < 8; ++jj) hb[jj] = f2h(sh[(quad * 8 + jj) * 65 + col]);
  const short8 s = {(short)hb[0], (short)hb[1], (short)hb[2], (short)hb[3],
                    (short)hb[4], (short)hb[5], (short)hb[6], (short)hb[7]};
  *(short8*)(Ef + (((size_t)kt * NIT + ig * 4 + itl) * 64 + lane) * 8) = s;
}

// ---- shared epilogue: p*(h@W_av+b_av) -> single f16 into LDS tile -----------
__device__ __forceinline__ void v_phase(const float* hs_row, float p,
    const float* __restrict__ W_av_k, const float* __restrict__ b_av_k,
    int r, int d4, unsigned short* shh) {
  float a[4] = {b_av_k[d4], b_av_k[d4 + 1], b_av_k[d4 + 2], b_av_k[d4 + 3]};
  for (int c = 0; c < DQ; ++c) {
    const float hv = hs_row[c];
    const float4 w = *(const float4*)&W_av_k[c * DQ + d4];
    a[0] += hv * w.x; a[1] += hv * w.y; a[2] += hv * w.z; a[3] += hv * w.w;
  }
  const int nt = d4 >> 4;
#pragma unroll
  for (int e = 0; e < 4; ++e)
    shh[nt * 128 + ((d4 + e) & 15) * 8 + r] = f2h(p * a[e]);
  const int c32 = d4 >> 2;
  if (c32 < 16)
    shh[8 * 128 + c32 * 8 + r] = (c32 == 0) ? f2h(p) : 0;
}

__device__ __forceinline__ void v_store(int tid, int blk,
    const unsigned short* shh, unsigned short* __restrict__ Vf) {
  const int kt = blk >> 2, quad = blk & 3;
  if (tid < NT * 16) {
    const int nt = tid >> 4, l15 = tid & 15;
    const size_t dst = (((size_t)kt * NT + nt) * 64 + quad * 16 + l15) * 8;
    *(short8*)(Vf + dst) = *(const short8*)&shh[nt * 128 + l15 * 8];
  }
}

// ---- round 0: encode + sa + p + V' fused (8 rows per block) ----
__global__ __launch_bounds__(256) void kVS0(const float* __restrict__ x,
    const float* __restrict__ comms, const float* __restrict__ W_enc,
    const float* __restrict__ b_enc, const float* __restrict__ W_ad_k,
    const float* __restrict__ wa, const float* __restrict__ W_av_k,
    const float* __restrict__ b_av_k, unsigned short* __restrict__ Vf) {
  __shared__ float xs[8][96];
  __shared__ float hs[8][DQ];
  __shared__ float u[DQ];
  __shared__ float pb[8];
  __shared__ __align__(16) unsigned short shh[NT * 128];
  const int tid = threadIdx.x;
  const int blk = blockIdx.x;
  if (tid < 128) {
    const float4 v = *(const float4*)&x[(size_t)blk * 8 * DIN + tid * 4];
    const int idx = tid * 4, r = idx >> 6, c = idx & 63;
    xs[r][c] = v.x; xs[r][c + 1] = v.y; xs[r][c + 2] = v.z; xs[r][c + 3] = v.w;
  } else if (tid < 192) {
    const int t = tid - 128;
    const float4 v = *(const float4*)&comms[(size_t)blk * 8 * DC + t * 4];
    const int idx = t * 4, r = idx >> 5, c = idx & 31;
    xs[r][64 + c] = v.x; xs[r][64 + c + 1] = v.y; xs[r][64 + c + 2] = v.z; xs[r][64 + c + 3] = v.w;
  }
  if (tid < DQ) {
    float s = 0.f;
    const float* wrow = &W_ad_k[tid * DQ];
    for (int q = 0; q < DQ; ++q) s += wrow[q] * wa[q];
    u[tid] = s;
  }
  __syncthreads();
  const int r = tid >> 5;
  const int c32 = tid & 31;
  const int d4 = c32 * 4;
  {
    float a0 = b_enc[d4], a1 = b_enc[d4 + 1], a2 = b_enc[d4 + 2], a3 = b_enc[d4 + 3];
    for (int c = 0; c < 96; ++c) {
      const float hv = xs[r][c];
      const float4 w = *(const float4*)&W_enc[c * DQ + d4];
      a0 += hv * w.x; a1 += hv * w.y; a2 += hv * w.z; a3 += hv * w.w;
    }
    hs[r][d4] = a0; hs[r][d4 + 1] = a1; hs[r][d4 + 2] = a2; hs[r][d4 + 3] = a3;
  }
  __syncthreads();
  float part = 0.f;
  for (int c = c32; c < DQ; c += 32) part += hs[r][c] * u[c];
#pragma unroll
  for (int m = 16; m > 0; m >>= 1) part += __shfl_xor(part, m, 32);
  if (c32 == 0) pb[r] = __expf(part);
  __syncthreads();
  v_phase(hs[r], pb[r], W_av_k, b_av_k, r, d4, shh);
  __syncthreads();
  v_store(tid, blk, shh, Vf);
}

// ---- round 1: P-reduce -> h + sa + p + V' (full panel) ----
__global__ __launch_bounds__(256) void kVSR(const float* __restrict__ P,
    const float* __restrict__ W_ad_k, const float* __restrict__ wa,
    const float* __restrict__ W_av_k, const float* __restrict__ b_av_k,
    unsigned short* __restrict__ Vf) {
  __shared__ float hs[8][DQ];
  __shared__ float u[DQ];
  __shared__ float pb[8];
  __shared__ __align__(16) unsigned short shh[NT * 128];
  const int tid = threadIdx.x;
  const int r = tid >> 5;
  const int c32 = tid & 31;
  const int d4 = c32 * 4;
  const int j = blockIdx.x * 8 + r;
  if (tid < DQ) {
    float s = 0.f;
    const float* wrow = &W_ad_k[tid * DQ];
    for (int q = 0; q < DQ; ++q) s += wrow[q] * wa[q];
    u[tid] = s;
  }
  float4 num = {0.f, 0.f, 0.f, 0.f};
  float den = 0.f;
#pragma unroll
  for (int s = 0; s < KB; ++s) {
    const float* b = &P[((size_t)s * N + j) * PST9];
    const float4 v = *(const float4*)&b[d4];
    num.x += v.x; num.y += v.y; num.z += v.z; num.w += v.w;
    den += b[128];
  }
  const float inv = 1.f / den;
  hs[r][d4] = num.x * inv; hs[r][d4 + 1] = num.y * inv;
  hs[r][d4 + 2] = num.z * inv; hs[r][d4 + 3] = num.w * inv;
  __syncthreads();
  float part = 0.f;
  for (int c = c32; c < DQ; c += 32) part += hs[r][c] * u[c];
#pragma unroll
  for (int m = 16; m > 0; m >>= 1) part += __shfl_xor(part, m, 32);
  if (c32 == 0) pb[r] = __expf(part);
  __syncthreads();
  v_phase(hs[r], pb[r], W_av_k, b_av_k, r, d4, shh);
  __syncthreads();
  v_store(tid, blockIdx.x, shh, Vf);
}

// ---- round 2: P-reduce -> h + sa + p + CONTRACTED V' (v.W_dec, p) ----
__global__ __launch_bounds__(256) void kVSRc(const float* __restrict__ P,
    const float* __restrict__ W_ad_k, const float* __restrict__ wa,
    const float* __restrict__ W_av_k, const float* __restrict__ b_av_k,
    const float* __restrict__ W_dec, unsigned short* __restrict__ Vc) {
  __shared__ float hs[8][DQ];
  __shared__ float u[DQ];
  __shared__ float pb[8];
  const int tid = threadIdx.x;
  const int r = tid >> 5;
  const int c32 = tid & 31;
  const int d4 = c32 * 4;
  const int j = blockIdx.x * 8 + r;
  if (tid < DQ) {
    float s = 0.f;
    const float* wrow = &W_ad_k[tid * DQ];
    for (int q = 0; q < DQ; ++q) s += wrow[q] * wa[q];
    u[tid] = s;
  }
  float4 num = {0.f, 0.f, 0.f, 0.f};
  float den = 0.f;
#pragma unroll
  for (int s = 0; s < KB; ++s) {
    const float* b = &P[((size_t)s * N + j) * PST9];
    const float4 v = *(const float4*)&b[d4];
    num.x += v.x; num.y += v.y; num.z += v.z; num.w += v.w;
    den += b[128];
  }
  const float inv = 1.f / den;
  hs[r][d4] = num.x * inv; hs[r][d4 + 1] = num.y * inv;
  hs[r][d4 + 2] = num.z * inv; hs[r][d4 + 3] = num.w * inv;
  __syncthreads();
  float part = 0.f;
  for (int c = c32; c < DQ; c += 32) part += hs[r][c] * u[c];
#pragma unroll
  for (int m = 16; m > 0; m >>= 1) part += __shfl_xor(part, m, 32);
  if (c32 == 0) pb[r] = __expf(part);
  __syncthreads();
  float a[4] = {b_av_k[d4], b_av_k[d4 + 1], b_av_k[d4 + 2], b_av_k[d4 + 3]};
  for (int c = 0; c < DQ; ++c) {
    const float hv = hs[r][c];
    const float4 w = *(const float4*)&W_av_k[c * DQ + d4];
    a[0] += hv * w.x; a[1] += hv * w.y; a[2] += hv * w.z; a[3] += hv * w.w;
  }
  float vd = a[0] * W_dec[d4] + a[1] * W_dec[d4 + 1]
           + a[2] * W_dec[d4 + 2] + a[3] * W_dec[d4 + 3];
#pragma unroll
  for (int m = 16; m > 0; m >>= 1) vd += __shfl_xor(vd, m, 32);
  const float p = pb[r];
  if (c32 < 16) {
    const int blk = blockIdx.x;
    const size_t ix = (((size_t)(blk >> 2)) * 64 + (blk & 3) * 16 + c32) * 8 + r;
    Vc[ix] = (c32 == 0) ? f2h(p * vd) : (c32 == 1) ? f2h(p) : 0;
  }
}

// ---- MFMA GEMM, in-block k-split: each of 4 waves covers SW=8 k-steps of the
// SAME 2 i-tiles with a wave-private LDS double-buffer (global_load_lds) and
// explicit s_waitcnt vmcnt(NTT+2) — no barriers in the k-loop. Epilogue:
// LDS-reduce the 4 wave-partials, one P write (KB=4 splits total).
template <int NTT, int PST>
__global__ __launch_bounds__(256) void kGemmR(
    const unsigned short* __restrict__ Ef, const unsigned short* __restrict__ Vf,
    float* __restrict__ P) {
  __shared__ __align__(16) unsigned short lds[4 * 2 * NTT * 512];
  const int tid = threadIdx.x;
  const int w = tid >> 6, lane = tid & 63;
  const int quad = lane >> 4, l15 = lane & 15;
  const int it0 = blockIdx.x * 2;
  const size_t ktw = (size_t)blockIdx.y * (4 * SW) + w * SW;
  unsigned short* myL = lds + w * (2 * NTT * 512);

  f32x4 acc[2][NTT];
#pragma unroll
  for (int ti = 0; ti < 2; ++ti)
#pragma unroll
    for (int nt = 0; nt < NTT; ++nt) acc[ti][nt] = (f32x4){0.f, 0.f, 0.f, 0.f};

  // prologue: stage step 0 panel + A(0)
#pragma unroll
  for (int c = 0; c < NTT; ++c)
    async16(myL + c * 512, Vf + (ktw * NTT + c) * 512 + lane * 8);
  half8 A0[2], A1[2];
#pragma unroll
  for (int ti = 0; ti < 2; ++ti)
    A0[ti] = __builtin_bit_cast(half8,
        *(const short8*)(Ef + ((ktw * NIT + it0 + ti) * 64 + lane) * 8));

#pragma unroll
  for (int t = 0; t < SW; ++t) {
    if (t + 1 < SW) {
      const size_t ktn = ktw + t + 1;
#pragma unroll
      for (int c = 0; c < NTT; ++c)
        async16(myL + ((t + 1) & 1) * NTT * 512 + c * 512,
                Vf + (ktn * NTT + c) * 512 + lane * 8);
#pragma unroll
      for (int ti = 0; ti < 2; ++ti)
        A1[ti] = __builtin_bit_cast(half8,
            *(const short8*)(Ef + ((ktn * NIT + it0 + ti) * 64 + lane) * 8));
      // keep t+1's NTT+2 ops in flight; drain step t's
      __builtin_amdgcn_s_waitcnt(0xF70 | (NTT + 2));
    } else {
      __builtin_amdgcn_s_waitcnt(0xF70);  // vmcnt(0): drain last step
    }
    const unsigned short* bb = myL + (t & 1) * NTT * 512;
#pragma unroll
    for (int nt = 0; nt < NTT; ++nt) {
      const half8 Bh = __builtin_bit_cast(half8,
          *(const short8*)(bb + nt * 512 + lane * 8));
      acc[0][nt] = __builtin_amdgcn_mfma_f32_16x16x32_f16(A0[0], Bh, acc[0][nt], 0, 0, 0);
      acc[1][nt] = __builtin_amdgcn_mfma_f32_16x16x32_f16(A0[1], Bh, acc[1][nt], 0, 0, 0);
    }
    if (t + 1 < SW) { A0[0] = A1[0]; A0[1] = A1[1]; }
  }
  // ---- in-block reduce: acc floats exactly fill the LDS ----
  __syncthreads();
  float* lf = (float*)lds;
#pragma unroll
  for (int ti = 0; ti < 2; ++ti)
#pragma unroll
    for (int nt = 0; nt < NTT; ++nt) {
      float4 v; v.x = acc[ti][nt][0]; v.y = acc[ti][nt][1];
      v.z = acc[ti][nt][2]; v.w = acc[ti][nt][3];
      *(float4*)&lf[(w * 2 * NTT + ti * NTT + nt) * 256 + lane * 4] = v;
    }
  __syncthreads();
  float* Pb = P + (size_t)blockIdx.y * N * PST;
  for (int p = w; p < 2 * NTT; p += 4) {
    const int ti = p / NTT, nt = p % NTT;
    float4 s = {0.f, 0.f, 0.f, 0.f};
#pragma unroll
    for (int wv = 0; wv < 4; ++wv) {
      const float4 v = *(const float4*)&lf[(wv * 2 * NTT + p) * 256 + lane * 4];
      s.x += v.x; s.y += v.y; s.z += v.z; s.w += v.w;
    }
    const float sr[4] = {s.x, s.y, s.z, s.w};
    if (NTT == 1 || nt != 8 || l15 == 0) {
#pragma unroll
      for (int r = 0; r < 4; ++r) {
        const int i = (it0 + ti) * 16 + quad * 4 + r;
        Pb[(size_t)i * PST + nt * 16 + l15] = sr[r];
      }
    }
  }
}

// ---- final: out[i] = numc/den + b_dec (P3 has 2 live cols) ----
__global__ __launch_bounds__(256) void kOut(const float* __restrict__ P3,
    const float* __restrict__ b_dec, const int* __restrict__ mask,
    float* __restrict__ out) {
  const int i = blockIdx.x * 256 + threadIdx.x;
  float num = 0.f, den = 0.f;
#pragma unroll
  for (int s = 0; s < KB; ++s) {
    const float* b = &P3[((size_t)s * N + i) * PST1];
    num += b[0];
    den += b[1];
  }
  out[i] = (mask[i] == 0) ? -INFINITY : num / den + b_dec[0];
}

extern "C" void kernel_launch(void* const* d_in, const int* in_sizes, int n_in,
                              void* d_out, int out_size, void* d_ws, size_t ws_size,
                              hipStream_t stream) {
  (void)in_sizes; (void)n_in; (void)out_size; (void)ws_size;
  const float* x     = (const float*)d_in[0];
  const float* comms = (const float*)d_in[1];
  const float* trans = (const float*)d_in[2];
  const int*   mask  = (const int*)d_in[3];
  const float* W_enc = (const float*)d_in[4];
  const float* b_enc = (const float*)d_in[5];
  const float* W_ad  = (const float*)d_in[6];
  // d_in[7]=b_ad, d_in[9]=b_att cancel inside the row softmax
  const float* w_att = (const float*)d_in[8];
  const float* W_av  = (const float*)d_in[10];
  const float* b_av  = (const float*)d_in[11];
  const float* W_dec = (const float*)d_in[12];
  const float* b_dec = (const float*)d_in[13];
  float* out         = (float*)d_out;

  char* ws = (char*)d_ws;
  unsigned short* Vf = (unsigned short*)ws;  ws += (size_t)(N / 32) * NT * 512 * 2;
  unsigned short* Vc = (unsigned short*)ws;  ws += (size_t)(N / 32) * 512 * 2;
  unsigned short* Ef = (unsigned short*)ws;  ws += (size_t)N * N * 2;
  float* P  = (float*)ws;                    ws += (size_t)KB * N * PST9 * 4;
  float* P3 = (float*)ws;

  kExp<<<dim3(64, 128), 256, 0, stream>>>(trans, Ef);
  kVS0<<<N / 8, 256, 0, stream>>>(x, comms, W_enc, b_enc, W_ad, w_att,
                                  W_av, b_av, Vf);
  kGemmR<NT, PST9><<<dim3(NIT / 2, KB), 256, 0, stream>>>(Ef, Vf, P);

  kVSR<<<N / 8, 256, 0, stream>>>(P, W_ad + (size_t)1 * DQ * DQ,
                                  w_att + 2 * DQ, W_av + (size_t)1 * DQ * DQ,
                                  b_av + DQ, Vf);
  kGemmR<NT, PST9><<<dim3(NIT / 2, KB), 256, 0, stream>>>(Ef, Vf, P);

  kVSRc<<<N / 8, 256, 0, stream>>>(P, W_ad + (size_t)2 * DQ * DQ,
                                   w_att + 4 * DQ, W_av + (size_t)2 * DQ * DQ,
                                   b_av + 2 * DQ, W_dec, Vc);
  kGemmR<1, PST1><<<dim3(NIT / 2, KB), 256, 0, stream>>>(Ef, Vc, P3);

  kOut<<<N / 256, 256, 0, stream>>>(P3, b_dec, mask, out);
}